// Round 17
// baseline (245.324 us; speedup 1.0000x reference)
//
#include <hip/hip_runtime.h>
#include <hip/hip_bf16.h>
#include <math.h>
#include <stdint.h>

#define D_MODEL 768
#define D_STATE 16
#define D_INNER 1536
#define DT_RANK 48
#define BATCH   2
#define SEQ     1024
#define NROWS   (BATCH*SEQ)      // 2048
#define DBC_N   80
#define DBC_NP  96               // padded N for xproj MFMA (was 128)
#define NCHUNK  64
#define CHUNK   16               // SEQ/NCHUNK
#define SCAN_G  (BATCH*NCHUNK*D_INNER)           // 196608 threads
#define SCAN_T  ((size_t)SCAN_G*D_STATE)         // 3145728 elems
#define LOG2E   1.44269504088896340736f

typedef short short8 __attribute__((ext_vector_type(8)));
typedef float floatx4 __attribute__((ext_vector_type(4)));

__device__ __forceinline__ float siluf(float x){ return x / (1.0f + __expf(-x)); }
__device__ __forceinline__ short f2b(float f){
    union { __hip_bfloat16 h; short s; } u; u.h = __float2bfloat16(f); return u.s;
}
__device__ __forceinline__ float b2f(short s){
    union { short s; __hip_bfloat16 h; } u; u.s = s; return __bfloat162float(u.h);
}
__device__ __forceinline__ void gload_lds16(const void* g, void* l){
    auto gp = reinterpret_cast<const __attribute__((address_space(1))) uint32_t*>(
        reinterpret_cast<uintptr_t>(g));
    auto lp = reinterpret_cast<__attribute__((address_space(3))) uint32_t*>(
        reinterpret_cast<uintptr_t>(l));
    __builtin_amdgcn_global_load_lds(gp, lp, 16, 0, 0);
}

// ---------------- prep: rmsnorm + transposes + dbc zero + residual copy -------
__device__ __forceinline__ void transp32(const float* in, short* outT,
                                         int R, int C, int Cout,
                                         int bx, int by, int t,
                                         float (*tile)[33]){
    int c0 = bx*32, r0 = by*32;
    int tx = t & 31, ty = t >> 5;
    #pragma unroll
    for (int p = 0; p < 4; p++){
        int r = r0 + ty + p*8, c = c0 + tx;
        tile[ty+p*8][tx] = (r < R && c < C) ? in[(size_t)r*C + c] : 0.f;
    }
    __syncthreads();
    #pragma unroll
    for (int p = 0; p < 4; p++){
        int c = c0 + ty + p*8;
        int r = r0 + tx;
        if (c < Cout && r < R)
            outT[(size_t)c*R + r] = f2b(tile[tx][ty+p*8]);
    }
}

// grid = 2048 rms + 2304 w1 + 1152 w3 + 144 wx + 160 dbc-zero + 384 out-copy = 6192
__global__ __launch_bounds__(256) void k_prep(const float* __restrict__ x,
                                              const float* __restrict__ nw,
                                              short* __restrict__ hb,
                                              const float* __restrict__ w1, short* __restrict__ Wb1,
                                              const float* __restrict__ w3, short* __restrict__ Wb3,
                                              const float* __restrict__ wx, short* __restrict__ Wbx,
                                              float* __restrict__ dbc,
                                              float* __restrict__ out){
    __shared__ float tile[32][33];
    int bid = blockIdx.x, t = threadIdx.x;
    if (bid < 2048){
        const float* xr = x + (size_t)bid * D_MODEL;
        float v[3]; float ss = 0.f;
        #pragma unroll
        for (int i = 0; i < 3; i++){ v[i] = xr[t + i*256]; ss += v[i]*v[i]; }
        #pragma unroll
        for (int o = 1; o < 64; o <<= 1) ss += __shfl_xor(ss, o, 64);
        int wave = t >> 6, lane = t & 63;
        if (lane == 0) tile[0][wave] = ss;
        __syncthreads();
        float tot = tile[0][0] + tile[0][1] + tile[0][2] + tile[0][3];
        float scale = rsqrtf(tot * (1.0f/768.0f) + 1e-6f);
        #pragma unroll
        for (int i = 0; i < 3; i++){
            int idx = t + i*256;
            hb[(size_t)bid*D_MODEL + idx] = f2b(v[i] * scale * nw[idx]);
        }
    } else if (bid < 4352){
        int id = bid - 2048;
        transp32(w1, Wb1, 768, 3072, 3072, id % 96, id / 96, t, tile);
    } else if (bid < 5504){
        int id = bid - 4352;
        transp32(w3, Wb3, 1536, 768, 768, id % 24, id / 24, t, tile);
    } else if (bid < 5648){
        int id = bid - 5504;
        transp32(wx, Wbx, 1536, DBC_N, DBC_NP, id % 3, id / 3, t, tile);
    } else if (bid < 5808){
        int id = bid - 5648;                      // zero 2048*80 floats
        size_t base = (size_t)id*1024 + t*4;
        *(float4*)&dbc[base] = make_float4(0.f,0.f,0.f,0.f);
    } else {
        int id = bid - 5808;                      // out = x (residual preload)
        #pragma unroll
        for (int p = 0; p < 4; p++){
            size_t off = (size_t)id*4096 + p*1024 + t*4;
            *(float4*)&out[off] = *(const float4*)&x[off];
        }
    }
}

// ---------------- MFMA bf16 GEMM, A[M][K] bf16, Bt[N][K] bf16 -----------------
// MODE 2: bf16 store. 3: fp32 atomicAdd (n<Nld).
// Round-11: BK=64 — halves barrier-pair count per K-loop (A/B'd: ~neutral).
template<int BM, int BN, int MODE, int KSPLIT>
__global__ __launch_bounds__(256) void k_mfma_bt(const short* __restrict__ A,
                                                 const short* __restrict__ Bt,
                                                 void* __restrict__ Cv,
                                                 int M, int N, int K, int Nld){
    constexpr int BK = 64;
    constexpr int WM = BM/2, WN = BN/2;
    constexpr int FM = WM/16, FN = WN/16;
    constexpr int AU = BM*(BK/8);   // 16B staging units (8 per row of 64 bf16)
    constexpr int BU = BN*(BK/8);
    constexpr int AR = (AU + 255)/256;
    constexpr int BR = (BU + 255)/256;
    __shared__ short As[BM*BK];
    __shared__ short Bs[BN*BK];
    int t = threadIdx.x;
    int wave = t >> 6, lane = t & 63;
    int lm = lane & 15, lq = lane >> 4;
    int row0 = blockIdx.y * BM, col0 = blockIdx.x * BN;
    int wr = (wave >> 1) * WM, wc = (wave & 1) * WN;
    int kper = K / KSPLIT;
    int kbeg = blockIdx.z * kper;
    floatx4 acc[FM][FN];
    #pragma unroll
    for (int mi = 0; mi < FM; mi++)
        #pragma unroll
        for (int ni = 0; ni < FN; ni++)
            acc[mi][ni] = (floatx4){0.f,0.f,0.f,0.f};

    for (int k0 = kbeg; k0 < kbeg + kper; k0 += BK){
        #pragma unroll
        for (int r2 = 0; r2 < AR; r2++){
            int slot = r2*256 + t;
            if ((AU % 256 == 0) || slot < AU){
                int ar = slot >> 3, ak = (slot & 7)*8;
                gload_lds16(A + (size_t)(row0+ar)*K + k0 + ak, &As[slot*8]);
            }
        }
        #pragma unroll
        for (int r2 = 0; r2 < BR; r2++){
            int slot = r2*256 + t;
            if ((BU % 256 == 0) || slot < BU){
                int br = slot >> 3, bk = (slot & 7)*8;
                gload_lds16(Bt + (size_t)(col0+br)*K + k0 + bk, &Bs[slot*8]);
            }
        }
        __syncthreads();
        #pragma unroll
        for (int kk = 0; kk < BK; kk += 32){
            short8 af[FM], bfr[FN];
            #pragma unroll
            for (int mi = 0; mi < FM; mi++)
                af[mi] = *(const short8*)&As[(wr + mi*16 + lm)*BK + kk + lq*8];
            #pragma unroll
            for (int ni = 0; ni < FN; ni++)
                bfr[ni] = *(const short8*)&Bs[(wc + ni*16 + lm)*BK + kk + lq*8];
            #pragma unroll
            for (int mi = 0; mi < FM; mi++)
                #pragma unroll
                for (int ni = 0; ni < FN; ni++)
                    acc[mi][ni] = __builtin_amdgcn_mfma_f32_16x16x32_bf16(
                                      af[mi], bfr[ni], acc[mi][ni], 0, 0, 0);
        }
        __syncthreads();
    }
    float* Cf = (float*)Cv;
    short* Cs = (short*)Cv;
    #pragma unroll
    for (int mi = 0; mi < FM; mi++)
        #pragma unroll
        for (int ni = 0; ni < FN; ni++)
            #pragma unroll
            for (int r = 0; r < 4; r++){
                int m = row0 + wr + mi*16 + lq*4 + r;
                int n = col0 + wc + ni*16 + lm;
                float v = acc[mi][ni][r];
                if constexpr (MODE == 2){
                    Cs[(size_t)m*Nld + n] = f2b(v);
                } else {
                    if (n < Nld) atomicAdd(&Cf[(size_t)m*Nld + n], v);
                }
            }
}

// ---------------- causal depthwise conv + bias + SiLU -> bf16 (8-wide) --------
__global__ __launch_bounds__(256) void k_conv(const short* __restrict__ xzb,
                                              const float* __restrict__ cw,
                                              const float* __restrict__ cb,
                                              short* __restrict__ xcb){
    int t = blockIdx.x * 256 + threadIdx.x;     // over NROWS * (D_INNER/8)
    int d8 = t % (D_INNER/8);
    int r  = t / (D_INNER/8);
    int d0 = d8 * 8;
    int l = r % SEQ;
    short8 tap[4];
    #pragma unroll
    for (int k = 0; k < 4; k++){
        if (l - 3 + k >= 0)
            tap[k] = *(const short8*)&xzb[(size_t)(r - 3 + k)*3072 + d0];
        else
            tap[k] = (short8){0,0,0,0,0,0,0,0};
    }
    short8 outv;
    #pragma unroll
    for (int j = 0; j < 8; j++){
        int d = d0 + j;
        const float4 w4 = *(const float4*)&cw[d*4];
        float acc = cb[d];
        acc += b2f(tap[0][j]) * w4.x;
        acc += b2f(tap[1][j]) * w4.y;
        acc += b2f(tap[2][j]) * w4.z;
        acc += b2f(tap[3][j]) * w4.w;
        outv[j] = f2b(siluf(acc));
    }
    *(short8*)&xcb[(size_t)r*D_INNER + d0] = outv;
}

// ================= chunked selective scan (dtproj fused into phase A) =========
// thread t = (b*NCHUNK + chunk)*D_INNER + d; Ap/Hl/carry bf16, layout [t][n].
// Round-2: dbc rows for the block's (b,chunk) staged in LDS once (5 KB);
// D_INNER = 6*256 so every 256-thread block lies in ONE (b,chunk) -> all
// dt-dot / B / C reads are wave-uniform LDS broadcasts (conflict-free).
// Round-5/8: A constants pre-scaled by log2(e); exp2f (HIP device fn ->
// v_exp_f32, which computes 2^x) deletes one v_mul per exp call
// (256 calls/thread in each of scanA/scanC). NOTE: __exp2f is CUDA-only —
// it collides with glibc math.h on HIP (R8 compile failure).

__global__ __launch_bounds__(256) void k_scanA(const short* __restrict__ xcb,
                                               const float* __restrict__ dbc,
                                               const float* __restrict__ wdt,
                                               const float* __restrict__ bdt,
                                               const float* __restrict__ A_log,
                                               short* __restrict__ Apb,
                                               short* __restrict__ Hlb,
                                               short* __restrict__ dtb){
    __shared__ float sdbc[CHUNK][DBC_N];        // 16*80*4 = 5120 B
    int t = blockIdx.x * 256 + threadIdx.x;
    int d = t % D_INNER;
    int bc = t / D_INNER;                        // block-uniform (1536 = 6*256)
    int chunk = bc % NCHUNK, b = bc / NCHUNK;
    int r0 = b*SEQ + chunk*CHUNK;

    {   // cooperative stage: 1280 contiguous floats
        const float* src = &dbc[(size_t)r0 * DBC_N];
        #pragma unroll
        for (int i = 0; i < CHUNK*DBC_N/256; i++){
            int idx = i*256 + threadIdx.x;
            ((float*)sdbc)[idx] = src[idx];
        }
    }
    __syncthreads();

    float dt16[CHUNK];
    {
        float wr[DT_RANK];
        #pragma unroll
        for (int k = 0; k < DT_RANK; k++) wr[k] = wdt[k*D_INNER + d];
        float bj = bdt[d];
        for (int l = 0; l < CHUNK; l++){
            float acc = bj;
            #pragma unroll
            for (int k = 0; k < DT_RANK; k++) acc += sdbc[l][k] * wr[k];
            float sp = (acc > 20.f) ? acc : __logf(1.f + __expf(acc));
            dt16[l] = sp;
            dtb[(size_t)(r0+l)*D_INNER + d] = f2b(sp);
        }
    }

    float A[16], h[16], aP[16];
    const float4* al = (const float4*)&A_log[d*D_STATE];
    #pragma unroll
    for (int i = 0; i < 4; i++){
        float4 v = al[i];
        A[4*i+0] = -__expf(v.x)*LOG2E; A[4*i+1] = -__expf(v.y)*LOG2E;
        A[4*i+2] = -__expf(v.z)*LOG2E; A[4*i+3] = -__expf(v.w)*LOG2E;
    }
    #pragma unroll
    for (int n = 0; n < 16; n++){ h[n] = 0.f; aP[n] = 1.f; }
    for (int l = 0; l < CHUNK; l++){
        int r = r0 + l;
        float dtv = dt16[l];
        float xcv = b2f(xcb[(size_t)r*D_INNER + d]);
        const float4* bp = (const float4*)&sdbc[l][DT_RANK];   // 16B-aligned
        float Bm[16];
        #pragma unroll
        for (int i = 0; i < 4; i++){
            float4 v = bp[i];
            Bm[4*i+0]=v.x; Bm[4*i+1]=v.y; Bm[4*i+2]=v.z; Bm[4*i+3]=v.w;
        }
        float comm = dtv * xcv;
        #pragma unroll
        for (int n = 0; n < 16; n++){
            float a = exp2f(dtv * A[n]);
            h[n] = a*h[n] + comm*Bm[n];
            aP[n] *= a;
        }
    }
    short8 s0, s1;
    #pragma unroll
    for (int i = 0; i < 8; i++){ s0[i] = f2b(aP[i]);  s1[i] = f2b(aP[8+i]); }
    *(short8*)&Apb[(size_t)t*16]     = s0;
    *(short8*)&Apb[(size_t)t*16 + 8] = s1;
    #pragma unroll
    for (int i = 0; i < 8; i++){ s0[i] = f2b(h[i]);   s1[i] = f2b(h[8+i]); }
    *(short8*)&Hlb[(size_t)t*16]     = s0;
    *(short8*)&Hlb[(size_t)t*16 + 8] = s1;
}

// carry aliases Apb: each idx read before written.
// Round-1 change: 8-deep manual pipeline. The alias (carry==Apb) forbids the
// compiler from hoisting loads across stores, serializing 64 memory round
// trips. Group-of-8: load 8 chunks' (a,h) into regs FIRST, then store+update.
// Within a group every stored address was already loaded; across groups the
// address sets are disjoint (monotone in ch). Bitwise-identical results.
__global__ __launch_bounds__(256) void k_scanB(const short* Apb,
                                               const short* Hlb,
                                               short* carry){
    int t = blockIdx.x * 256 + threadIdx.x;    // over [b][d][n/2] = 24576
    int dn2 = t % (D_INNER*8);
    int b   = t / (D_INNER*8);
    size_t base0 = ((size_t)b*NCHUNK*D_INNER)*16 + (size_t)dn2*2;
    const size_t step = (size_t)D_INNER*16;
    float c0 = 0.f, c1 = 0.f;
    for (int g = 0; g < NCHUNK; g += 8){
        int ua8[8], uh8[8];
        #pragma unroll
        for (int j = 0; j < 8; j++){
            size_t idx = base0 + (size_t)(g + j)*step;
            ua8[j] = *(const int*)&Apb[idx];
            uh8[j] = *(const int*)&Hlb[idx];
        }
        #pragma unroll
        for (int j = 0; j < 8; j++){
            size_t idx = base0 + (size_t)(g + j)*step;
            union { int i; short s[2]; } ua, uh, uc;
            ua.i = ua8[j]; uh.i = uh8[j];
            uc.s[0] = f2b(c0); uc.s[1] = f2b(c1);
            *(int*)&carry[idx] = uc.i;
            c0 = b2f(ua.s[0])*c0 + b2f(uh.s[0]);
            c1 = b2f(ua.s[1])*c1 + b2f(uh.s[1]);
        }
    }
}

__global__ __launch_bounds__(256) void k_scanC(const short* __restrict__ dtb,
                                               const short* __restrict__ xcb,
                                               const float* __restrict__ dbc,
                                               const short* __restrict__ xzb,
                                               const float* __restrict__ A_log,
                                               const float* __restrict__ Dp,
                                               const short* __restrict__ carry,
                                               short* __restrict__ yb){
    __shared__ float sdbc[CHUNK][DBC_N];        // 5120 B, see k_scanA note
    int t = blockIdx.x * 256 + threadIdx.x;
    int d = t % D_INNER;
    int bc = t / D_INNER;                        // block-uniform
    int chunk = bc % NCHUNK, b = bc / NCHUNK;
    int r0 = b*SEQ + chunk*CHUNK;

    {
        const float* src = &dbc[(size_t)r0 * DBC_N];
        #pragma unroll
        for (int i = 0; i < CHUNK*DBC_N/256; i++){
            int idx = i*256 + threadIdx.x;
            ((float*)sdbc)[idx] = src[idx];
        }
    }
    __syncthreads();

    float A[16], h[16];
    const float4* al = (const float4*)&A_log[d*D_STATE];
    #pragma unroll
    for (int i = 0; i < 4; i++){
        float4 v = al[i];
        A[4*i+0] = -__expf(v.x)*LOG2E; A[4*i+1] = -__expf(v.y)*LOG2E;
        A[4*i+2] = -__expf(v.z)*LOG2E; A[4*i+3] = -__expf(v.w)*LOG2E;
    }
    {
        short8 c0 = *(const short8*)&carry[(size_t)t*16];
        short8 c1 = *(const short8*)&carry[(size_t)t*16 + 8];
        #pragma unroll
        for (int i = 0; i < 8; i++){ h[i] = b2f(c0[i]); h[8+i] = b2f(c1[i]); }
    }
    float Dv = Dp[d];
    for (int l = 0; l < CHUNK; l++){
        int r = r0 + l;
        float dtv = b2f(dtb[(size_t)r*D_INNER + d]);
        float xcv = b2f(xcb[(size_t)r*D_INNER + d]);
        const float4* bp = (const float4*)&sdbc[l][DT_RANK];
        float Bm[16], Cm[16];
        #pragma unroll
        for (int i = 0; i < 4; i++){
            float4 v = bp[i];
            Bm[4*i+0]=v.x; Bm[4*i+1]=v.y; Bm[4*i+2]=v.z; Bm[4*i+3]=v.w;
            float4 w = bp[4+i];
            Cm[4*i+0]=w.x; Cm[4*i+1]=w.y; Cm[4*i+2]=w.z; Cm[4*i+3]=w.w;
        }
        float comm = dtv * xcv;
        float yv = 0.f;
        #pragma unroll
        for (int n = 0; n < 16; n++){
            float a = exp2f(dtv * A[n]);
            h[n] = a*h[n] + comm*Bm[n];
            yv += h[n]*Cm[n];
        }
        float z = b2f(xzb[(size_t)r*(2*D_INNER) + D_INNER + d]);
        yb[(size_t)r*D_INNER + d] = f2b((yv + Dv*xcv) * siluf(z));
    }
}

extern "C" void kernel_launch(void* const* d_in, const int* in_sizes, int n_in,
                              void* d_out, int out_size, void* d_ws, size_t ws_size,
                              hipStream_t stream) {
    const float* x         = (const float*)d_in[0];
    const float* norm_w    = (const float*)d_in[1];
    const float* in_proj_w = (const float*)d_in[2];
    const float* conv_w    = (const float*)d_in[3];
    const float* conv_b    = (const float*)d_in[4];
    const float* x_proj_w  = (const float*)d_in[5];
    const float* dt_proj_w = (const float*)d_in[6];
    const float* dt_proj_b = (const float*)d_in[7];
    const float* A_log     = (const float*)d_in[8];
    const float* Dp        = (const float*)d_in[9];
    const float* out_proj_w= (const float*)d_in[10];
    float* out = (float*)d_out;

    char* p = (char*)d_ws;
    short* hb  = (short*)p; p += (size_t)NROWS*D_MODEL*2;
    short* xzb = (short*)p; p += (size_t)NROWS*3072*2;
    short* xcb = (short*)p; p += (size_t)NROWS*D_INNER*2;
    float* dbc = (float*)p; p += (size_t)NROWS*DBC_N*4;
    short* dtb = (short*)p; p += (size_t)NROWS*D_INNER*2;
    short* yb  = (short*)p; p += (size_t)NROWS*D_INNER*2;
    short* Apb = (short*)p; p += SCAN_T*2;                     // aliased as carry
    short* Hlb = (short*)p; p += SCAN_T*2;
    short* Wb1 = (short*)p; p += (size_t)3072*768*2;
    short* Wb3 = (short*)p; p += (size_t)768*1536*2;
    short* Wbx = (short*)p; p += (size_t)DBC_NP*1536*2;
    short* cr  = Apb;  // alias: k_scanB reads before writing at each idx

    // rmsnorm + transposes + dbc zero + residual preload into out
    k_prep<<<6192, 256, 0, stream>>>(x, norm_w, hb, in_proj_w, Wb1,
                                     out_proj_w, Wb3, x_proj_w, Wbx, dbc, out);

    // ---- R15 PROBE: in-proj x3 (idempotent overwrite; MODE 2) -----------
    // Delta vs 206.5 = 2*T_inproj + 2*1.55us. Downstream reads after 3rd
    // identical write -> outputs bitwise unchanged.
    for (int rep = 0; rep < 3; rep++)
        k_mfma_bt<64,96,2,1><<<dim3(3072/96, NROWS/64), 256, 0, stream>>>(
            hb, Wb1, xzb, NROWS, 3072, D_MODEL, 3072);

    // conv (8-wide vectorized, coalesced)
    k_conv<<<(NROWS*(D_INNER/8))/256, 256, 0, stream>>>(xzb, conv_w, conv_b, xcb);

    // x-proj: M=2048, N=96(pad of 80), K=1536, split-K=8 -> 256 blocks
    k_mfma_bt<64,96,3,8><<<dim3(DBC_NP/96, NROWS/64, 8), 256, 0, stream>>>(
        xcb, Wbx, dbc, NROWS, DBC_NP, D_INNER, DBC_N);

    // scan: A (dtproj fused, LDS-staged dbc, exp2) -> B (8-deep pipelined) ->
    //       C (LDS-staged dbc, exp2)   (bf16 intermediates)
    k_scanA<<<SCAN_G/256, 256, 0, stream>>>(xcb, dbc, dt_proj_w, dt_proj_b,
                                            A_log, Apb, Hlb, dtb);
    k_scanB<<<(BATCH*D_INNER*D_STATE/2)/256, 256, 0, stream>>>(Apb, Hlb, cr);
    k_scanC<<<SCAN_G/256, 256, 0, stream>>>(dtb, xcb, dbc, xzb, A_log, Dp,
                                            cr, yb);

    // out-proj: M=2048, N=768, K=1536, split-K=2 -> 768 blocks, atomicAdd
    // (residual preloaded into out by k_prep)
    k_mfma_bt<64,64,3,2><<<dim3(768/64, NROWS/64, 2), 256, 0, stream>>>(
        yb, Wb3, out, NROWS, 768, D_INNER, 768);
}

// Round 18
// 205.691 us; speedup vs baseline: 1.1927x; 1.1927x over previous
//
#include <hip/hip_runtime.h>
#include <hip/hip_bf16.h>
#include <math.h>
#include <stdint.h>

#define D_MODEL 768
#define D_STATE 16
#define D_INNER 1536
#define DT_RANK 48
#define BATCH   2
#define SEQ     1024
#define NROWS   (BATCH*SEQ)      // 2048
#define DBC_N   80
#define DBC_NP  96               // padded N for xproj MFMA (was 128)
#define NCHUNK  64
#define CHUNK   16               // SEQ/NCHUNK
#define SCAN_G  (BATCH*NCHUNK*D_INNER)           // 196608 threads
#define SCAN_T  ((size_t)SCAN_G*D_STATE)         // 3145728 elems
#define LOG2E   1.44269504088896340736f

typedef short short8 __attribute__((ext_vector_type(8)));
typedef float floatx4 __attribute__((ext_vector_type(4)));

__device__ __forceinline__ float siluf(float x){ return x / (1.0f + __expf(-x)); }
__device__ __forceinline__ short f2b(float f){
    union { __hip_bfloat16 h; short s; } u; u.h = __float2bfloat16(f); return u.s;
}
__device__ __forceinline__ float b2f(short s){
    union { short s; __hip_bfloat16 h; } u; u.s = s; return __bfloat162float(u.h);
}
__device__ __forceinline__ void gload_lds16(const void* g, void* l){
    auto gp = reinterpret_cast<const __attribute__((address_space(1))) uint32_t*>(
        reinterpret_cast<uintptr_t>(g));
    auto lp = reinterpret_cast<__attribute__((address_space(3))) uint32_t*>(
        reinterpret_cast<uintptr_t>(l));
    __builtin_amdgcn_global_load_lds(gp, lp, 16, 0, 0);
}

// ---------------- prep: rmsnorm + transposes + dbc zero + residual copy -------
__device__ __forceinline__ void transp32(const float* in, short* outT,
                                         int R, int C, int Cout,
                                         int bx, int by, int t,
                                         float (*tile)[33]){
    int c0 = bx*32, r0 = by*32;
    int tx = t & 31, ty = t >> 5;
    #pragma unroll
    for (int p = 0; p < 4; p++){
        int r = r0 + ty + p*8, c = c0 + tx;
        tile[ty+p*8][tx] = (r < R && c < C) ? in[(size_t)r*C + c] : 0.f;
    }
    __syncthreads();
    #pragma unroll
    for (int p = 0; p < 4; p++){
        int c = c0 + ty + p*8;
        int r = r0 + tx;
        if (c < Cout && r < R)
            outT[(size_t)c*R + r] = f2b(tile[tx][ty+p*8]);
    }
}

// grid = 2048 rms + 2304 w1 + 1152 w3 + 144 wx + 160 dbc-zero + 384 out-copy = 6192
__global__ __launch_bounds__(256) void k_prep(const float* __restrict__ x,
                                              const float* __restrict__ nw,
                                              short* __restrict__ hb,
                                              const float* __restrict__ w1, short* __restrict__ Wb1,
                                              const float* __restrict__ w3, short* __restrict__ Wb3,
                                              const float* __restrict__ wx, short* __restrict__ Wbx,
                                              float* __restrict__ dbc,
                                              float* __restrict__ out){
    __shared__ float tile[32][33];
    int bid = blockIdx.x, t = threadIdx.x;
    if (bid < 2048){
        const float* xr = x + (size_t)bid * D_MODEL;
        float v[3]; float ss = 0.f;
        #pragma unroll
        for (int i = 0; i < 3; i++){ v[i] = xr[t + i*256]; ss += v[i]*v[i]; }
        #pragma unroll
        for (int o = 1; o < 64; o <<= 1) ss += __shfl_xor(ss, o, 64);
        int wave = t >> 6, lane = t & 63;
        if (lane == 0) tile[0][wave] = ss;
        __syncthreads();
        float tot = tile[0][0] + tile[0][1] + tile[0][2] + tile[0][3];
        float scale = rsqrtf(tot * (1.0f/768.0f) + 1e-6f);
        #pragma unroll
        for (int i = 0; i < 3; i++){
            int idx = t + i*256;
            hb[(size_t)bid*D_MODEL + idx] = f2b(v[i] * scale * nw[idx]);
        }
    } else if (bid < 4352){
        int id = bid - 2048;
        transp32(w1, Wb1, 768, 3072, 3072, id % 96, id / 96, t, tile);
    } else if (bid < 5504){
        int id = bid - 4352;
        transp32(w3, Wb3, 1536, 768, 768, id % 24, id / 24, t, tile);
    } else if (bid < 5648){
        int id = bid - 5504;
        transp32(wx, Wbx, 1536, DBC_N, DBC_NP, id % 3, id / 3, t, tile);
    } else if (bid < 5808){
        int id = bid - 5648;                      // zero 2048*80 floats
        size_t base = (size_t)id*1024 + t*4;
        *(float4*)&dbc[base] = make_float4(0.f,0.f,0.f,0.f);
    } else {
        int id = bid - 5808;                      // out = x (residual preload)
        #pragma unroll
        for (int p = 0; p < 4; p++){
            size_t off = (size_t)id*4096 + p*1024 + t*4;
            *(float4*)&out[off] = *(const float4*)&x[off];
        }
    }
}

// ---------------- MFMA bf16 GEMM, A[M][K] bf16, Bt[N][K] bf16 -----------------
// MODE 2: bf16 store. 3: fp32 atomicAdd (n<Nld).
// Round-11: BK=64 — halves barrier-pair count per K-loop (A/B'd: ~neutral).
// R15 probe: in-proj measured ~17.9us warm (~540 TF) — near the 2-phase
// structure's plateau for K=768; micro-edits null (R11/R13).
template<int BM, int BN, int MODE, int KSPLIT>
__global__ __launch_bounds__(256) void k_mfma_bt(const short* __restrict__ A,
                                                 const short* __restrict__ Bt,
                                                 void* __restrict__ Cv,
                                                 int M, int N, int K, int Nld){
    constexpr int BK = 64;
    constexpr int WM = BM/2, WN = BN/2;
    constexpr int FM = WM/16, FN = WN/16;
    constexpr int AU = BM*(BK/8);   // 16B staging units (8 per row of 64 bf16)
    constexpr int BU = BN*(BK/8);
    constexpr int AR = (AU + 255)/256;
    constexpr int BR = (BU + 255)/256;
    __shared__ short As[BM*BK];
    __shared__ short Bs[BN*BK];
    int t = threadIdx.x;
    int wave = t >> 6, lane = t & 63;
    int lm = lane & 15, lq = lane >> 4;
    int row0 = blockIdx.y * BM, col0 = blockIdx.x * BN;
    int wr = (wave >> 1) * WM, wc = (wave & 1) * WN;
    int kper = K / KSPLIT;
    int kbeg = blockIdx.z * kper;
    floatx4 acc[FM][FN];
    #pragma unroll
    for (int mi = 0; mi < FM; mi++)
        #pragma unroll
        for (int ni = 0; ni < FN; ni++)
            acc[mi][ni] = (floatx4){0.f,0.f,0.f,0.f};

    for (int k0 = kbeg; k0 < kbeg + kper; k0 += BK){
        #pragma unroll
        for (int r2 = 0; r2 < AR; r2++){
            int slot = r2*256 + t;
            if ((AU % 256 == 0) || slot < AU){
                int ar = slot >> 3, ak = (slot & 7)*8;
                gload_lds16(A + (size_t)(row0+ar)*K + k0 + ak, &As[slot*8]);
            }
        }
        #pragma unroll
        for (int r2 = 0; r2 < BR; r2++){
            int slot = r2*256 + t;
            if ((BU % 256 == 0) || slot < BU){
                int br = slot >> 3, bk = (slot & 7)*8;
                gload_lds16(Bt + (size_t)(col0+br)*K + k0 + bk, &Bs[slot*8]);
            }
        }
        __syncthreads();
        #pragma unroll
        for (int kk = 0; kk < BK; kk += 32){
            short8 af[FM], bfr[FN];
            #pragma unroll
            for (int mi = 0; mi < FM; mi++)
                af[mi] = *(const short8*)&As[(wr + mi*16 + lm)*BK + kk + lq*8];
            #pragma unroll
            for (int ni = 0; ni < FN; ni++)
                bfr[ni] = *(const short8*)&Bs[(wc + ni*16 + lm)*BK + kk + lq*8];
            #pragma unroll
            for (int mi = 0; mi < FM; mi++)
                #pragma unroll
                for (int ni = 0; ni < FN; ni++)
                    acc[mi][ni] = __builtin_amdgcn_mfma_f32_16x16x32_bf16(
                                      af[mi], bfr[ni], acc[mi][ni], 0, 0, 0);
        }
        __syncthreads();
    }
    float* Cf = (float*)Cv;
    short* Cs = (short*)Cv;
    #pragma unroll
    for (int mi = 0; mi < FM; mi++)
        #pragma unroll
        for (int ni = 0; ni < FN; ni++)
            #pragma unroll
            for (int r = 0; r < 4; r++){
                int m = row0 + wr + mi*16 + lq*4 + r;
                int n = col0 + wc + ni*16 + lm;
                float v = acc[mi][ni][r];
                if constexpr (MODE == 2){
                    Cs[(size_t)m*Nld + n] = f2b(v);
                } else {
                    if (n < Nld) atomicAdd(&Cf[(size_t)m*Nld + n], v);
                }
            }
}

// ---------------- causal depthwise conv + bias + SiLU -> bf16 (8-wide) --------
__global__ __launch_bounds__(256) void k_conv(const short* __restrict__ xzb,
                                              const float* __restrict__ cw,
                                              const float* __restrict__ cb,
                                              short* __restrict__ xcb){
    int t = blockIdx.x * 256 + threadIdx.x;     // over NROWS * (D_INNER/8)
    int d8 = t % (D_INNER/8);
    int r  = t / (D_INNER/8);
    int d0 = d8 * 8;
    int l = r % SEQ;
    short8 tap[4];
    #pragma unroll
    for (int k = 0; k < 4; k++){
        if (l - 3 + k >= 0)
            tap[k] = *(const short8*)&xzb[(size_t)(r - 3 + k)*3072 + d0];
        else
            tap[k] = (short8){0,0,0,0,0,0,0,0};
    }
    short8 outv;
    #pragma unroll
    for (int j = 0; j < 8; j++){
        int d = d0 + j;
        const float4 w4 = *(const float4*)&cw[d*4];
        float acc = cb[d];
        acc += b2f(tap[0][j]) * w4.x;
        acc += b2f(tap[1][j]) * w4.y;
        acc += b2f(tap[2][j]) * w4.z;
        acc += b2f(tap[3][j]) * w4.w;
        outv[j] = f2b(siluf(acc));
    }
    *(short8*)&xcb[(size_t)r*D_INNER + d0] = outv;
}

// ================= chunked selective scan (dtproj fused into phase A) =========
// thread t = (b*NCHUNK + chunk)*D_INNER + d; Ap/Hl/carry bf16, layout [t][n].
// Round-2: dbc rows staged in LDS (5 KB); all dt-dot / B / C reads are
// wave-uniform LDS broadcasts. Round-5/8: exp2f with log2e-folded A.
// Round-17: dtb round-trip ELIMINATED — scanC recomputes dt from its own
// sdbc stage (same formula, full f32; previously scanC read a bf16-rounded
// copy). Saves 12.6 MB of traffic + 16 stores/thread in scanA.

__global__ __launch_bounds__(256) void k_scanA(const short* __restrict__ xcb,
                                               const float* __restrict__ dbc,
                                               const float* __restrict__ wdt,
                                               const float* __restrict__ bdt,
                                               const float* __restrict__ A_log,
                                               short* __restrict__ Apb,
                                               short* __restrict__ Hlb){
    __shared__ float sdbc[CHUNK][DBC_N];        // 16*80*4 = 5120 B
    int t = blockIdx.x * 256 + threadIdx.x;
    int d = t % D_INNER;
    int bc = t / D_INNER;                        // block-uniform (1536 = 6*256)
    int chunk = bc % NCHUNK, b = bc / NCHUNK;
    int r0 = b*SEQ + chunk*CHUNK;

    {   // cooperative stage: 1280 contiguous floats
        const float* src = &dbc[(size_t)r0 * DBC_N];
        #pragma unroll
        for (int i = 0; i < CHUNK*DBC_N/256; i++){
            int idx = i*256 + threadIdx.x;
            ((float*)sdbc)[idx] = src[idx];
        }
    }
    __syncthreads();

    float dt16[CHUNK];
    {
        float wr[DT_RANK];
        #pragma unroll
        for (int k = 0; k < DT_RANK; k++) wr[k] = wdt[k*D_INNER + d];
        float bj = bdt[d];
        for (int l = 0; l < CHUNK; l++){
            float acc = bj;
            #pragma unroll
            for (int k = 0; k < DT_RANK; k++) acc += sdbc[l][k] * wr[k];
            dt16[l] = (acc > 20.f) ? acc : __logf(1.f + __expf(acc));
        }
    }

    float A[16], h[16], aP[16];
    const float4* al = (const float4*)&A_log[d*D_STATE];
    #pragma unroll
    for (int i = 0; i < 4; i++){
        float4 v = al[i];
        A[4*i+0] = -__expf(v.x)*LOG2E; A[4*i+1] = -__expf(v.y)*LOG2E;
        A[4*i+2] = -__expf(v.z)*LOG2E; A[4*i+3] = -__expf(v.w)*LOG2E;
    }
    #pragma unroll
    for (int n = 0; n < 16; n++){ h[n] = 0.f; aP[n] = 1.f; }
    for (int l = 0; l < CHUNK; l++){
        int r = r0 + l;
        float dtv = dt16[l];
        float xcv = b2f(xcb[(size_t)r*D_INNER + d]);
        const float4* bp = (const float4*)&sdbc[l][DT_RANK];   // 16B-aligned
        float Bm[16];
        #pragma unroll
        for (int i = 0; i < 4; i++){
            float4 v = bp[i];
            Bm[4*i+0]=v.x; Bm[4*i+1]=v.y; Bm[4*i+2]=v.z; Bm[4*i+3]=v.w;
        }
        float comm = dtv * xcv;
        #pragma unroll
        for (int n = 0; n < 16; n++){
            float a = exp2f(dtv * A[n]);
            h[n] = a*h[n] + comm*Bm[n];
            aP[n] *= a;
        }
    }
    short8 s0, s1;
    #pragma unroll
    for (int i = 0; i < 8; i++){ s0[i] = f2b(aP[i]);  s1[i] = f2b(aP[8+i]); }
    *(short8*)&Apb[(size_t)t*16]     = s0;
    *(short8*)&Apb[(size_t)t*16 + 8] = s1;
    #pragma unroll
    for (int i = 0; i < 8; i++){ s0[i] = f2b(h[i]);   s1[i] = f2b(h[8+i]); }
    *(short8*)&Hlb[(size_t)t*16]     = s0;
    *(short8*)&Hlb[(size_t)t*16 + 8] = s1;
}

// carry aliases Apb: each idx read before written.
// Round-1 change: 8-deep manual pipeline. The alias (carry==Apb) forbids the
// compiler from hoisting loads across stores, serializing 64 memory round
// trips. Group-of-8: load 8 chunks' (a,h) into regs FIRST, then store+update.
// Within a group every stored address was already loaded; across groups the
// address sets are disjoint (monotone in ch). Bitwise-identical results.
__global__ __launch_bounds__(256) void k_scanB(const short* Apb,
                                               const short* Hlb,
                                               short* carry){
    int t = blockIdx.x * 256 + threadIdx.x;    // over [b][d][n/2] = 24576
    int dn2 = t % (D_INNER*8);
    int b   = t / (D_INNER*8);
    size_t base0 = ((size_t)b*NCHUNK*D_INNER)*16 + (size_t)dn2*2;
    const size_t step = (size_t)D_INNER*16;
    float c0 = 0.f, c1 = 0.f;
    for (int g = 0; g < NCHUNK; g += 8){
        int ua8[8], uh8[8];
        #pragma unroll
        for (int j = 0; j < 8; j++){
            size_t idx = base0 + (size_t)(g + j)*step;
            ua8[j] = *(const int*)&Apb[idx];
            uh8[j] = *(const int*)&Hlb[idx];
        }
        #pragma unroll
        for (int j = 0; j < 8; j++){
            size_t idx = base0 + (size_t)(g + j)*step;
            union { int i; short s[2]; } ua, uh, uc;
            ua.i = ua8[j]; uh.i = uh8[j];
            uc.s[0] = f2b(c0); uc.s[1] = f2b(c1);
            *(int*)&carry[idx] = uc.i;
            c0 = b2f(ua.s[0])*c0 + b2f(uh.s[0]);
            c1 = b2f(ua.s[1])*c1 + b2f(uh.s[1]);
        }
    }
}

__global__ __launch_bounds__(256) void k_scanC(const short* __restrict__ xcb,
                                               const float* __restrict__ dbc,
                                               const float* __restrict__ wdt,
                                               const float* __restrict__ bdt,
                                               const short* __restrict__ xzb,
                                               const float* __restrict__ A_log,
                                               const float* __restrict__ Dp,
                                               const short* __restrict__ carry,
                                               short* __restrict__ yb){
    __shared__ float sdbc[CHUNK][DBC_N];        // 5120 B, see k_scanA note
    int t = blockIdx.x * 256 + threadIdx.x;
    int d = t % D_INNER;
    int bc = t / D_INNER;                        // block-uniform
    int chunk = bc % NCHUNK, b = bc / NCHUNK;
    int r0 = b*SEQ + chunk*CHUNK;

    {
        const float* src = &dbc[(size_t)r0 * DBC_N];
        #pragma unroll
        for (int i = 0; i < CHUNK*DBC_N/256; i++){
            int idx = i*256 + threadIdx.x;
            ((float*)sdbc)[idx] = src[idx];
        }
    }
    __syncthreads();

    float dt16[CHUNK];
    {   // R17: recompute dt here (identical formula to scanA, full f32)
        float wr[DT_RANK];
        #pragma unroll
        for (int k = 0; k < DT_RANK; k++) wr[k] = wdt[k*D_INNER + d];
        float bj = bdt[d];
        for (int l = 0; l < CHUNK; l++){
            float acc = bj;
            #pragma unroll
            for (int k = 0; k < DT_RANK; k++) acc += sdbc[l][k] * wr[k];
            dt16[l] = (acc > 20.f) ? acc : __logf(1.f + __expf(acc));
        }
    }

    float A[16], h[16];
    const float4* al = (const float4*)&A_log[d*D_STATE];
    #pragma unroll
    for (int i = 0; i < 4; i++){
        float4 v = al[i];
        A[4*i+0] = -__expf(v.x)*LOG2E; A[4*i+1] = -__expf(v.y)*LOG2E;
        A[4*i+2] = -__expf(v.z)*LOG2E; A[4*i+3] = -__expf(v.w)*LOG2E;
    }
    {
        short8 c0 = *(const short8*)&carry[(size_t)t*16];
        short8 c1 = *(const short8*)&carry[(size_t)t*16 + 8];
        #pragma unroll
        for (int i = 0; i < 8; i++){ h[i] = b2f(c0[i]); h[8+i] = b2f(c1[i]); }
    }
    float Dv = Dp[d];
    for (int l = 0; l < CHUNK; l++){
        int r = r0 + l;
        float dtv = dt16[l];
        float xcv = b2f(xcb[(size_t)r*D_INNER + d]);
        const float4* bp = (const float4*)&sdbc[l][DT_RANK];
        float Bm[16], Cm[16];
        #pragma unroll
        for (int i = 0; i < 4; i++){
            float4 v = bp[i];
            Bm[4*i+0]=v.x; Bm[4*i+1]=v.y; Bm[4*i+2]=v.z; Bm[4*i+3]=v.w;
            float4 w = bp[4+i];
            Cm[4*i+0]=w.x; Cm[4*i+1]=w.y; Cm[4*i+2]=w.z; Cm[4*i+3]=w.w;
        }
        float comm = dtv * xcv;
        float yv = 0.f;
        #pragma unroll
        for (int n = 0; n < 16; n++){
            float a = exp2f(dtv * A[n]);
            h[n] = a*h[n] + comm*Bm[n];
            yv += h[n]*Cm[n];
        }
        float z = b2f(xzb[(size_t)r*(2*D_INNER) + D_INNER + d]);
        yb[(size_t)r*D_INNER + d] = f2b((yv + Dv*xcv) * siluf(z));
    }
}

extern "C" void kernel_launch(void* const* d_in, const int* in_sizes, int n_in,
                              void* d_out, int out_size, void* d_ws, size_t ws_size,
                              hipStream_t stream) {
    const float* x         = (const float*)d_in[0];
    const float* norm_w    = (const float*)d_in[1];
    const float* in_proj_w = (const float*)d_in[2];
    const float* conv_w    = (const float*)d_in[3];
    const float* conv_b    = (const float*)d_in[4];
    const float* x_proj_w  = (const float*)d_in[5];
    const float* dt_proj_w = (const float*)d_in[6];
    const float* dt_proj_b = (const float*)d_in[7];
    const float* A_log     = (const float*)d_in[8];
    const float* Dp        = (const float*)d_in[9];
    const float* out_proj_w= (const float*)d_in[10];
    float* out = (float*)d_out;

    char* p = (char*)d_ws;
    short* hb  = (short*)p; p += (size_t)NROWS*D_MODEL*2;
    short* xzb = (short*)p; p += (size_t)NROWS*3072*2;
    short* xcb = (short*)p; p += (size_t)NROWS*D_INNER*2;
    float* dbc = (float*)p; p += (size_t)NROWS*DBC_N*4;
    short* dtb = (short*)p; p += (size_t)NROWS*D_INNER*2;   // R17: slot unused (kept to preserve verified layout)
    short* yb  = (short*)p; p += (size_t)NROWS*D_INNER*2;
    short* Apb = (short*)p; p += SCAN_T*2;                     // aliased as carry
    short* Hlb = (short*)p; p += SCAN_T*2;
    short* Wb1 = (short*)p; p += (size_t)3072*768*2;
    short* Wb3 = (short*)p; p += (size_t)768*1536*2;
    short* Wbx = (short*)p; p += (size_t)DBC_NP*1536*2;
    short* cr  = Apb;  // alias: k_scanB reads before writing at each idx
    (void)dtb;

    // rmsnorm + transposes + dbc zero + residual preload into out
    k_prep<<<6192, 256, 0, stream>>>(x, norm_w, hb, in_proj_w, Wb1,
                                     out_proj_w, Wb3, x_proj_w, Wbx, dbc, out);

    // in-proj: M=2048, N=3072, K=768, 64x96 tiles -> 1024 blocks (4/CU)
    k_mfma_bt<64,96,2,1><<<dim3(3072/96, NROWS/64), 256, 0, stream>>>(
        hb, Wb1, xzb, NROWS, 3072, D_MODEL, 3072);

    // conv (8-wide vectorized, coalesced)
    k_conv<<<(NROWS*(D_INNER/8))/256, 256, 0, stream>>>(xzb, conv_w, conv_b, xcb);

    // x-proj: M=2048, N=96(pad of 80), K=1536, split-K=8 -> 256 blocks
    k_mfma_bt<64,96,3,8><<<dim3(DBC_NP/96, NROWS/64, 8), 256, 0, stream>>>(
        xcb, Wbx, dbc, NROWS, DBC_NP, D_INNER, DBC_N);

    // scan: A (dtproj fused, LDS-staged dbc, exp2) -> B (8-deep pipelined) ->
    //       C (recomputes dt locally; dtb round-trip eliminated, R17)
    k_scanA<<<SCAN_G/256, 256, 0, stream>>>(xcb, dbc, dt_proj_w, dt_proj_b,
                                            A_log, Apb, Hlb);
    k_scanB<<<(BATCH*D_INNER*D_STATE/2)/256, 256, 0, stream>>>(Apb, Hlb, cr);
    k_scanC<<<SCAN_G/256, 256, 0, stream>>>(xcb, dbc, dt_proj_w, dt_proj_b,
                                            xzb, A_log, Dp, cr, yb);

    // out-proj: M=2048, N=768, K=1536, split-K=2 -> 768 blocks, atomicAdd
    // (residual preloaded into out by k_prep)
    k_mfma_bt<64,64,3,2><<<dim3(768/64, NROWS/64, 2), 256, 0, stream>>>(
        yb, Wb3, out, NROWS, 768, D_INNER, 768);
}